// Round 4
// baseline (464.508 us; speedup 1.0000x reference)
//
#include <hip/hip_runtime.h>

// Problem constants
#define N_ 64
#define H_ 256
#define W_ 256
#define C_ 16
#define O_ 16

// Row-streaming config: block = 256 threads = one full row (thread = column x),
// each block slides over CH consecutive output rows of one image.
// grid = (H/CH, N) = (16, 64) = 1024 blocks = exactly 4 blocks/CU -> ALL resident.
#define CH 16
#define PLANE 258   // float4 granules per channel-plane row (+2 guard cols)

// LDS: t rows (t = in . w^T), 2 row slots x 4 channel-planes x PLANE float4.
// Plane-major layout: lane x touches granule (x+1) -> stride-1 across lanes for
// every write and every +/-1 tap read => zero bank conflicts, no padding waste.
// 2*4*258*16 = 33,024 B -> 4 blocks/CU (132 KB of 160 KB).

__device__ __forceinline__ void load_row(const float* __restrict__ base, int r, int x,
                                         float4 pf[4]) {
    const float4* s4 = (const float4*)(base + ((size_t)r * W_ + x) * C_);
    #pragma unroll
    for (int q = 0; q < 4; ++q) pf[q] = s4[q];
}

__device__ __forceinline__ void cmix(const float* __restrict__ w, const float4 pf[4],
                                     float tn[16]) {
    const float iv[16] = {pf[0].x, pf[0].y, pf[0].z, pf[0].w,
                          pf[1].x, pf[1].y, pf[1].z, pf[1].w,
                          pf[2].x, pf[2].y, pf[2].z, pf[2].w,
                          pf[3].x, pf[3].y, pf[3].z, pf[3].w};
    #pragma unroll
    for (int l = 0; l < 16; ++l) {
        float s = 0.f;
        #pragma unroll
        for (int k = 0; k < 16; ++k) s = fmaf(w[l * 16 + k], iv[k], s);
        tn[l] = s;
    }
}

__device__ __forceinline__ void write_t(float4* __restrict__ lds, int slot, int x,
                                        const float tn[16]) {
    #pragma unroll
    for (int q = 0; q < 4; ++q)
        lds[(slot * 4 + q) * PLANE + (x + 1)] =
            make_float4(tn[4 * q], tn[4 * q + 1], tn[4 * q + 2], tn[4 * q + 3]);
}

// h[l] = u[l][0]*t[x-1][l] + u[l][1]*t[x][l] + u[l][2]*t[x+1][l]
// center tap comes from registers (tn); neighbors from LDS (guard cols give 0).
__device__ __forceinline__ void hrow(const float4* __restrict__ lds, int slot, int x,
                                     const float* __restrict__ u, const float tn[16],
                                     float h[16]) {
    float4 m4[4], p4[4];
    #pragma unroll
    for (int q = 0; q < 4; ++q) {
        m4[q] = lds[(slot * 4 + q) * PLANE + x];       // column x-1 (stored at x+1)
        p4[q] = lds[(slot * 4 + q) * PLANE + x + 2];   // column x+1
    }
    const float tm[16] = {m4[0].x, m4[0].y, m4[0].z, m4[0].w,
                          m4[1].x, m4[1].y, m4[1].z, m4[1].w,
                          m4[2].x, m4[2].y, m4[2].z, m4[2].w,
                          m4[3].x, m4[3].y, m4[3].z, m4[3].w};
    const float tp[16] = {p4[0].x, p4[0].y, p4[0].z, p4[0].w,
                          p4[1].x, p4[1].y, p4[1].z, p4[1].w,
                          p4[2].x, p4[2].y, p4[2].z, p4[2].w,
                          p4[3].x, p4[3].y, p4[3].z, p4[3].w};
    #pragma unroll
    for (int l = 0; l < 16; ++l)
        h[l] = fmaf(u[l * 3 + 0], tm[l],
               fmaf(u[l * 3 + 2], tp[l], u[l * 3 + 1] * tn[l]));
}

__global__ __launch_bounds__(256, 4)
void sep_conv_kernel(const float* __restrict__ in,
                     const float* __restrict__ u,   // (O,K) = (16,3)
                     const float* __restrict__ v,   // (O,K)
                     const float* __restrict__ w,   // (O,C) = (16,16)
                     const float* __restrict__ b,   // (O)
                     float* __restrict__ out) {
    __shared__ float4 t_lds[2 * 4 * PLANE];  // 33,024 B

    const int x  = threadIdx.x;        // column 0..255
    const int y0 = blockIdx.x * CH;    // first output row of this chunk
    const int n  = blockIdx.y;

    const float* inb  = in  + (size_t)n * H_ * W_ * C_;
    float*       outb = out + (size_t)n * H_ * W_ * C_;   // O_ == C_

    // zero the guard columns once (2 slots x 4 planes x 2 sides = 16 float4)
    if (x < 16) {
        const int slot = x >> 3, q = (x >> 1) & 3, side = x & 1;
        t_lds[(slot * 4 + q) * PLANE + (side ? PLANE - 1 : 0)] =
            make_float4(0.f, 0.f, 0.f, 0.f);
    }

    float4 pf[4];
    float tn[16], hp[16], hc[16], hn[16];

    // ---- warmup: h(y0-1) -> hp, h(y0) -> hc ----
    const int rm1 = y0 - 1;
    const bool have_m1 = (rm1 >= 0);
    if (have_m1) {
        load_row(inb, rm1, x, pf);
        cmix(w, pf, tn);
    }
    load_row(inb, y0, x, pf);          // issue early; pf already consumed (or unused)
    if (have_m1) write_t(t_lds, rm1 & 1, x, tn);
    __syncthreads();                   // also publishes the guard zeros
    if (have_m1) {
        hrow(t_lds, rm1 & 1, x, u, tn, hp);
    } else {
        #pragma unroll
        for (int l = 0; l < 16; ++l) hp[l] = 0.f;
    }

    cmix(w, pf, tn);                   // row y0
    load_row(inb, y0 + 1, x, pf);      // prefetch (y0+1 <= 241 < H always)
    write_t(t_lds, y0 & 1, x, tn);
    __syncthreads();
    hrow(t_lds, y0 & 1, x, u, tn, hc);

    // ---- steady state: one output row per iteration ----
    for (int yy = 0; yy < CH; ++yy) {
        const int y  = y0 + yy;        // output row
        const int rn = y + 1;          // row whose t/h we produce this iteration
        if (rn < H_) {                 // uniform across block
            cmix(w, pf, tn);           // consumes prefetched row rn
            if (yy + 1 < CH && rn + 1 < H_)
                load_row(inb, rn + 1, x, pf);   // prefetch next; hides HBM latency
            write_t(t_lds, rn & 1, x, tn);
            __syncthreads();
            hrow(t_lds, rn & 1, x, u, tn, hn);
        } else {
            #pragma unroll
            for (int l = 0; l < 16; ++l) hn[l] = 0.f;
        }

        // out[y] = relu(b + v0*h[y-1] + v1*h[y] + v2*h[y+1])
        float r[16];
        #pragma unroll
        for (int l = 0; l < 16; ++l) {
            float val = fmaf(v[l * 3 + 0], hp[l],
                        fmaf(v[l * 3 + 1], hc[l],
                        fmaf(v[l * 3 + 2], hn[l], b[l])));
            r[l] = fmaxf(val, 0.f);
        }
        float4* o4 = (float4*)(outb + ((size_t)y * W_ + x) * C_);
        o4[0] = make_float4(r[0],  r[1],  r[2],  r[3]);
        o4[1] = make_float4(r[4],  r[5],  r[6],  r[7]);
        o4[2] = make_float4(r[8],  r[9],  r[10], r[11]);
        o4[3] = make_float4(r[12], r[13], r[14], r[15]);

        // rotate the h ring (explicit copies keep all indexing compile-time)
        #pragma unroll
        for (int l = 0; l < 16; ++l) { hp[l] = hc[l]; hc[l] = hn[l]; }
    }
}

extern "C" void kernel_launch(void* const* d_in, const int* in_sizes, int n_in,
                              void* d_out, int out_size, void* d_ws, size_t ws_size,
                              hipStream_t stream) {
    const float* in = (const float*)d_in[0];
    const float* u  = (const float*)d_in[1];
    const float* v  = (const float*)d_in[2];
    const float* w  = (const float*)d_in[3];
    const float* b  = (const float*)d_in[4];
    float* out = (float*)d_out;

    dim3 grid(H_ / CH, N_);   // 16 x 64 = 1024 blocks = 4/CU, all resident
    dim3 block(256);
    sep_conv_kernel<<<grid, block, 0, stream>>>(in, u, v, w, b, out);
}